// Round 6
// baseline (170.044 us; speedup 1.0000x reference)
//
#include <hip/hip_runtime.h>

namespace {

constexpr int kN = 100;   // subactors
constexpr int kH = 16;    // hidden
constexpr int kS = 6;     // state
constexpr int kB = 128;   // batch
constexpr int kT = 128;   // time
constexpr int kNS = kN * kS;   // 600 floats per (b,t) row
constexpr int kXB = kT * kNS;  // 76800 floats per b
// phase-1 h stash: per (n,bt,t): 64 lanes x 2 dwords = 512 B
constexpr size_t kWsNeed = (size_t)kN * 8 * kT * 128 * 4;  // 52.4 MB

typedef float f32x4 __attribute__((ext_vector_type(4)));
typedef short bf16x8 __attribute__((ext_vector_type(8)));
typedef unsigned u32x2 __attribute__((ext_vector_type(2)));

union Frag {
  unsigned u[4];
  bf16x8 v;
};

// RNE pack of two f32 into one dword of two bf16 (low = a). Manual bit twiddle
// (__hip_bfloat162 is not trivially copyable -> no __builtin_bit_cast on it).
__device__ __forceinline__ unsigned pkbf(float a, float b) {
  unsigned ua = __builtin_bit_cast(unsigned, a);
  unsigned ub = __builtin_bit_cast(unsigned, b);
  ua += 0x7fffu + ((ua >> 16) & 1u);
  ub += 0x7fffu + ((ub >> 16) & 1u);
  return (ua >> 16) | (ub & 0xffff0000u);
}

__device__ __forceinline__ float rcp_fast(float v) {
  return __builtin_amdgcn_rcpf(v);
}
__device__ __forceinline__ float sigm(float v) {
  return rcp_fast(1.0f + __expf(-v));
}
__device__ __forceinline__ float tanh_fast(float v) {
  return 1.0f - 2.0f * rcp_fast(1.0f + __expf(2.0f * v));
}

__device__ __forceinline__ f32x4 mfma16(bf16x8 a, bf16x8 b, f32x4 c) {
  return __builtin_amdgcn_mfma_f32_16x16x32_bf16(a, b, c, 0, 0, 0);
}

// Build a static A fragment: rows j, K = [h(16) | x(6) | 0...].
// A layout (HW-verified): m = lane&15, k = qt*8 + i.
__device__ __forceinline__ void mkA(Frag& F, int qt, const float* hrow,
                                    const float* xrow) {
  F.u[0] = F.u[1] = F.u[2] = F.u[3] = 0u;
  if (qt == 0 && hrow) {
    F.u[0] = pkbf(hrow[0], hrow[1]);
    F.u[1] = pkbf(hrow[2], hrow[3]);
    F.u[2] = pkbf(hrow[4], hrow[5]);
    F.u[3] = pkbf(hrow[6], hrow[7]);
  }
  if (qt == 1 && hrow) {
    F.u[0] = pkbf(hrow[8], hrow[9]);
    F.u[1] = pkbf(hrow[10], hrow[11]);
    F.u[2] = pkbf(hrow[12], hrow[13]);
    F.u[3] = pkbf(hrow[14], hrow[15]);
  }
  if (qt == 2 && xrow) {  // k 16..21 = x, rest 0
    F.u[0] = pkbf(xrow[0], xrow[1]);
    F.u[1] = pkbf(xrow[2], xrow[3]);
    F.u[2] = pkbf(xrow[4], xrow[5]);
  }
}

}  // namespace

// ---------------------------------------------------------------------------
// Phase 1: GRU recurrence only. Wave = (n, 16-batch tile). Per step: one
// bpermute cluster -> 4 MFMAs -> gate epilogue -> pack h (reused next step)
// -> coalesced 8B/lane store of packed h to ws.
// ---------------------------------------------------------------------------
__global__ __launch_bounds__(64) void gru_mfma(
    const float* __restrict__ x, const float* __restrict__ Wih,
    const float* __restrict__ Whh, const float* __restrict__ bih,
    const float* __restrict__ bhh, unsigned* __restrict__ hws) {
  const int tid = (int)threadIdx.x;
  const int j = tid & 15;
  const int qt = tid >> 4;
  const int n = (int)blockIdx.x >> 3;
  const int bt = (int)blockIdx.x & 7;

  Frag Ar, Az, Anh, Anx;
  mkA(Ar, qt, Whh + ((size_t)n * 48 + j) * 16, Wih + ((size_t)n * 48 + j) * 6);
  mkA(Az, qt, Whh + ((size_t)n * 48 + 16 + j) * 16,
      Wih + ((size_t)n * 48 + 16 + j) * 6);
  mkA(Anh, qt, Whh + ((size_t)n * 48 + 32 + j) * 16, nullptr);
  mkA(Anx, qt, nullptr, Wih + ((size_t)n * 48 + 32 + j) * 6);

  float br_[4], bz_[4], bin_[4], bhn_[4];
#pragma unroll
  for (int r = 0; r < 4; ++r) {
    const int gi = n * 48 + 4 * qt + r;
    br_[r] = bih[gi] + bhh[gi];
    bz_[r] = bih[gi + 16] + bhh[gi + 16];
    bin_[r] = bih[gi + 32];
    bhn_[r] = bhh[gi + 32];
  }

  const int a_lo = (j + 32 * (qt & 1)) * 4;
  const int a_hi = a_lo + 64;

  const int b = bt * 16 + j;
  const float* px = x + (size_t)b * kXB + (size_t)n * kS;
  unsigned* hwp = hws + ((size_t)(n * 8 + bt) * kT) * 128 + tid * 2;

  const f32x4 zero4 = {0.f, 0.f, 0.f, 0.f};

  // x register pipeline, depth 4
  float2 xs[4][3];
#pragma unroll
  for (int i = 0; i < 4; ++i) {
    const float* xp = px + (size_t)i * kNS;
    xs[i][0] = *(const float2*)(xp + 0);
    xs[i][1] = *(const float2*)(xp + 2);
    xs[i][2] = *(const float2*)(xp + 4);
  }

  float hprev[4] = {0.f, 0.f, 0.f, 0.f};
  unsigned P0 = 0u, P1 = 0u;  // packed bf16 h (carried across steps)

  for (int t4 = 0; t4 < kT; t4 += 4) {
#pragma unroll
    for (int k = 0; k < 4; ++k) {
      const int t = t4 + k;
      // B h-part via one bpermute cluster on the carried packed h
      const int bp0 = __builtin_amdgcn_ds_bpermute(a_lo, (int)P0);
      const int bp1 = __builtin_amdgcn_ds_bpermute(a_lo, (int)P1);
      const int bp2 = __builtin_amdgcn_ds_bpermute(a_hi, (int)P0);
      const int bp3 = __builtin_amdgcn_ds_bpermute(a_hi, (int)P1);
      const unsigned xd0 = pkbf(xs[k][0].x, xs[k][0].y);
      const unsigned xd1 = pkbf(xs[k][1].x, xs[k][1].y);
      const unsigned xd2 = pkbf(xs[k][2].x, xs[k][2].y);
      Frag Bf;
      Bf.u[0] = (qt < 2) ? (unsigned)bp0 : ((qt == 2) ? xd0 : 0u);
      Bf.u[1] = (qt < 2) ? (unsigned)bp1 : ((qt == 2) ? xd1 : 0u);
      Bf.u[2] = (qt < 2) ? (unsigned)bp2 : ((qt == 2) ? xd2 : 0u);
      Bf.u[3] = (qt < 2) ? (unsigned)bp3 : 0u;

      // reload this x stage with t+4
      {
        int tc = t + 4;
        if (tc > kT - 1) tc = kT - 1;
        const float* xp = px + (size_t)tc * kNS;
        xs[k][0] = *(const float2*)(xp + 0);
        xs[k][1] = *(const float2*)(xp + 2);
        xs[k][2] = *(const float2*)(xp + 4);
      }

      const f32x4 Cr = mfma16(Ar.v, Bf.v, zero4);    // xr + hr
      const f32x4 Cz = mfma16(Az.v, Bf.v, zero4);    // xz + hz
      const f32x4 Chn = mfma16(Anh.v, Bf.v, zero4);  // hn only
      const f32x4 Cxn = mfma16(Anx.v, Bf.v, zero4);  // xn only

      // gate epilogue -> h_t
#pragma unroll
      for (int r = 0; r < 4; ++r) {
        const float rr = sigm(Cr[r] + br_[r]);
        const float zz = sigm(Cz[r] + bz_[r]);
        const float nn =
            tanh_fast((Cxn[r] + bin_[r]) + rr * (Chn[r] + bhn_[r]));
        hprev[r] = nn + zz * (hprev[r] - nn);
      }

      // pack once: feeds next step's bpermute AND the ws store
      P0 = pkbf(hprev[0], hprev[1]);
      P1 = pkbf(hprev[2], hprev[3]);
      *(u32x2*)(hwp + (size_t)t * 128) = (u32x2){P0, P1};
    }
  }
}

// ---------------------------------------------------------------------------
// Phase 2: MLP head. Wave = (n, 16-batch tile, 32-t chunk) -> 3200 waves,
// no serial dependency across t (fully pipelined t-loop).
// ---------------------------------------------------------------------------
__global__ __launch_bounds__(64) void mlp_mfma(
    const unsigned* __restrict__ hws, const float* __restrict__ W1,
    const float* __restrict__ b1, const float* __restrict__ W2,
    const float* __restrict__ b2, const float* __restrict__ W3,
    const float* __restrict__ b3, float* __restrict__ out) {
  const int tid = (int)threadIdx.x;
  const int j = tid & 15;
  const int qt = tid >> 4;
  const int n = (int)blockIdx.x >> 3;
  const int bt = (int)blockIdx.x & 7;
  const int t0 = (int)blockIdx.y * 32;

  Frag Ay1, Ay2;
  mkA(Ay1, qt, W1 + ((size_t)n * 16 + j) * 16, nullptr);
  mkA(Ay2, qt, W2 + ((size_t)n * 16 + j) * 16, nullptr);

  float b1e[4], b2e[4], w3r[4];
#pragma unroll
  for (int r = 0; r < 4; ++r) {
    const int hi = n * 16 + 4 * qt + r;
    b1e[r] = b1[hi];
    b2e[r] = b2[hi];
    w3r[r] = W3[hi];
  }
  const float b3s = b3[n];

  const int a_lo = (j + 32 * (qt & 1)) * 4;
  const int a_hi = a_lo + 64;

  const unsigned* hwp = hws + ((size_t)(n * 8 + bt) * kT) * 128 + tid * 2;
  float* outp = out + ((size_t)n * kB + bt * 16 + j) * kT;

  const f32x4 zero4 = {0.f, 0.f, 0.f, 0.f};

#pragma unroll 2
  for (int t = t0; t < t0 + 32; ++t) {
    const u32x2 P = *(const u32x2*)(hwp + (size_t)t * 128);
    const int bp0 = __builtin_amdgcn_ds_bpermute(a_lo, (int)P.x);
    const int bp1 = __builtin_amdgcn_ds_bpermute(a_lo, (int)P.y);
    const int bp2 = __builtin_amdgcn_ds_bpermute(a_hi, (int)P.x);
    const int bp3 = __builtin_amdgcn_ds_bpermute(a_hi, (int)P.y);
    Frag Bh;
    Bh.u[0] = (qt < 2) ? (unsigned)bp0 : 0u;
    Bh.u[1] = (qt < 2) ? (unsigned)bp1 : 0u;
    Bh.u[2] = (qt < 2) ? (unsigned)bp2 : 0u;
    Bh.u[3] = (qt < 2) ? (unsigned)bp3 : 0u;

    const f32x4 Cy1 = mfma16(Ay1.v, Bh.v, zero4);
    float y1v[4];
#pragma unroll
    for (int r = 0; r < 4; ++r) y1v[r] = fmaxf(Cy1[r] + b1e[r], 0.f);
    const unsigned Q0 = pkbf(y1v[0], y1v[1]);
    const unsigned Q1 = pkbf(y1v[2], y1v[3]);
    const int yb0 = __builtin_amdgcn_ds_bpermute(a_lo, (int)Q0);
    const int yb1 = __builtin_amdgcn_ds_bpermute(a_lo, (int)Q1);
    const int yb2 = __builtin_amdgcn_ds_bpermute(a_hi, (int)Q0);
    const int yb3 = __builtin_amdgcn_ds_bpermute(a_hi, (int)Q1);
    Frag By;
    By.u[0] = (qt < 2) ? (unsigned)yb0 : 0u;
    By.u[1] = (qt < 2) ? (unsigned)yb1 : 0u;
    By.u[2] = (qt < 2) ? (unsigned)yb2 : 0u;
    By.u[3] = (qt < 2) ? (unsigned)yb3 : 0u;

    const f32x4 Cy2 = mfma16(Ay2.v, By.v, zero4);
    float s = 0.f;
#pragma unroll
    for (int r = 0; r < 4; ++r) s += fmaxf(Cy2[r] + b2e[r], 0.f) * w3r[r];
    s += __shfl_xor(s, 16);
    s += __shfl_xor(s, 32);
    if (qt == 0) outp[t] = fmaxf(s + b3s, 0.f);
  }
}

// ---------------------------------------------------------------------------
// Fallback: round-5 monolithic kernel (used only if ws_size < 52.4 MB).
// ---------------------------------------------------------------------------
__global__ __launch_bounds__(64) void actor_mfma(
    const float* __restrict__ x, const float* __restrict__ Wih,
    const float* __restrict__ Whh, const float* __restrict__ bih,
    const float* __restrict__ bhh, const float* __restrict__ W1,
    const float* __restrict__ b1, const float* __restrict__ W2,
    const float* __restrict__ b2, const float* __restrict__ W3,
    const float* __restrict__ b3, float* __restrict__ out) {
  const int tid = (int)threadIdx.x;
  const int j = tid & 15;
  const int qt = tid >> 4;
  const int n = (int)blockIdx.x >> 3;
  const int bt = (int)blockIdx.x & 7;

  Frag Ar, Az, Anh, Anx, Ay1, Ay2;
  mkA(Ar, qt, Whh + ((size_t)n * 48 + j) * 16, Wih + ((size_t)n * 48 + j) * 6);
  mkA(Az, qt, Whh + ((size_t)n * 48 + 16 + j) * 16,
      Wih + ((size_t)n * 48 + 16 + j) * 6);
  mkA(Anh, qt, Whh + ((size_t)n * 48 + 32 + j) * 16, nullptr);
  mkA(Anx, qt, nullptr, Wih + ((size_t)n * 48 + 32 + j) * 6);
  mkA(Ay1, qt, W1 + ((size_t)n * 16 + j) * 16, nullptr);
  mkA(Ay2, qt, W2 + ((size_t)n * 16 + j) * 16, nullptr);

  float br_[4], bz_[4], bin_[4], bhn_[4], b1e[4], b2e[4], w3r[4];
#pragma unroll
  for (int r = 0; r < 4; ++r) {
    const int gi = n * 48 + 4 * qt + r;
    br_[r] = bih[gi] + bhh[gi];
    bz_[r] = bih[gi + 16] + bhh[gi + 16];
    bin_[r] = bih[gi + 32];
    bhn_[r] = bhh[gi + 32];
    const int hi = n * 16 + 4 * qt + r;
    b1e[r] = b1[hi];
    b2e[r] = b2[hi];
    w3r[r] = W3[hi];
  }
  const float b3s = b3[n];

  const int a_lo = (j + 32 * (qt & 1)) * 4;
  const int a_hi = a_lo + 64;

  const int b = bt * 16 + j;
  const float* px = x + (size_t)b * kXB + (size_t)n * kS;
  float* outp = out + ((size_t)n * kB + b) * kT;

  const f32x4 zero4 = {0.f, 0.f, 0.f, 0.f};

  float2 xs[4][3];
#pragma unroll
  for (int i = 0; i < 4; ++i) {
    const float* xp = px + (size_t)i * kNS;
    xs[i][0] = *(const float2*)(xp + 0);
    xs[i][1] = *(const float2*)(xp + 2);
    xs[i][2] = *(const float2*)(xp + 4);
  }

  float hprev[4] = {0.f, 0.f, 0.f, 0.f};

  auto doY = [&](const f32x4& Cy1, int tout) {
    float y1v[4];
#pragma unroll
    for (int r = 0; r < 4; ++r) y1v[r] = fmaxf(Cy1[r] + b1e[r], 0.f);
    const unsigned Q0 = pkbf(y1v[0], y1v[1]);
    const unsigned Q1 = pkbf(y1v[2], y1v[3]);
    const int yb0 = __builtin_amdgcn_ds_bpermute(a_lo, (int)Q0);
    const int yb1 = __builtin_amdgcn_ds_bpermute(a_lo, (int)Q1);
    const int yb2 = __builtin_amdgcn_ds_bpermute(a_hi, (int)Q0);
    const int yb3 = __builtin_amdgcn_ds_bpermute(a_hi, (int)Q1);
    Frag By;
    By.u[0] = (qt < 2) ? (unsigned)yb0 : 0u;
    By.u[1] = (qt < 2) ? (unsigned)yb1 : 0u;
    By.u[2] = (qt < 2) ? (unsigned)yb2 : 0u;
    By.u[3] = (qt < 2) ? (unsigned)yb3 : 0u;
    const f32x4 Cy2 = mfma16(Ay2.v, By.v, zero4);
    float s = 0.f;
#pragma unroll
    for (int r = 0; r < 4; ++r) s += fmaxf(Cy2[r] + b2e[r], 0.f) * w3r[r];
    s += __shfl_xor(s, 16);
    s += __shfl_xor(s, 32);
    const float y3 = fmaxf(s + b3s, 0.f);
    if (tout >= 0 && qt == 0) outp[tout] = y3;
  };

  auto doStep = [&](int t, int st) {
    const unsigned P0 = pkbf(hprev[0], hprev[1]);
    const unsigned P1 = pkbf(hprev[2], hprev[3]);
    const int bp0 = __builtin_amdgcn_ds_bpermute(a_lo, (int)P0);
    const int bp1 = __builtin_amdgcn_ds_bpermute(a_lo, (int)P1);
    const int bp2 = __builtin_amdgcn_ds_bpermute(a_hi, (int)P0);
    const int bp3 = __builtin_amdgcn_ds_bpermute(a_hi, (int)P1);
    const unsigned xd0 = pkbf(xs[st][0].x, xs[st][0].y);
    const unsigned xd1 = pkbf(xs[st][1].x, xs[st][1].y);
    const unsigned xd2 = pkbf(xs[st][2].x, xs[st][2].y);
    Frag Bf;
    Bf.u[0] = (qt < 2) ? (unsigned)bp0 : ((qt == 2) ? xd0 : 0u);
    Bf.u[1] = (qt < 2) ? (unsigned)bp1 : ((qt == 2) ? xd1 : 0u);
    Bf.u[2] = (qt < 2) ? (unsigned)bp2 : ((qt == 2) ? xd2 : 0u);
    Bf.u[3] = (qt < 2) ? (unsigned)bp3 : 0u;

    {
      int tc = t + 4;
      if (tc > kT - 1) tc = kT - 1;
      const float* xp = px + (size_t)tc * kNS;
      xs[st][0] = *(const float2*)(xp + 0);
      xs[st][1] = *(const float2*)(xp + 2);
      xs[st][2] = *(const float2*)(xp + 4);
    }

    const f32x4 Cr = mfma16(Ar.v, Bf.v, zero4);
    const f32x4 Cz = mfma16(Az.v, Bf.v, zero4);
    const f32x4 Chn = mfma16(Anh.v, Bf.v, zero4);
    const f32x4 Cxn = mfma16(Anx.v, Bf.v, zero4);
    const f32x4 Cy1 = mfma16(Ay1.v, Bf.v, zero4);

    doY(Cy1, t - 1);

#pragma unroll
    for (int r = 0; r < 4; ++r) {
      const float rr = sigm(Cr[r] + br_[r]);
      const float zz = sigm(Cz[r] + bz_[r]);
      const float nn =
          tanh_fast((Cxn[r] + bin_[r]) + rr * (Chn[r] + bhn_[r]));
      hprev[r] = nn + zz * (hprev[r] - nn);
    }
  };

  for (int t4 = 0; t4 < kT; t4 += 4) {
    doStep(t4 + 0, 0);
    doStep(t4 + 1, 1);
    doStep(t4 + 2, 2);
    doStep(t4 + 3, 3);
  }

  {
    const unsigned P0 = pkbf(hprev[0], hprev[1]);
    const unsigned P1 = pkbf(hprev[2], hprev[3]);
    const int bp0 = __builtin_amdgcn_ds_bpermute(a_lo, (int)P0);
    const int bp1 = __builtin_amdgcn_ds_bpermute(a_lo, (int)P1);
    const int bp2 = __builtin_amdgcn_ds_bpermute(a_hi, (int)P0);
    const int bp3 = __builtin_amdgcn_ds_bpermute(a_hi, (int)P1);
    Frag Bf;
    Bf.u[0] = (qt < 2) ? (unsigned)bp0 : 0u;
    Bf.u[1] = (qt < 2) ? (unsigned)bp1 : 0u;
    Bf.u[2] = (qt < 2) ? (unsigned)bp2 : 0u;
    Bf.u[3] = (qt < 2) ? (unsigned)bp3 : 0u;
    const f32x4 Cy1 = mfma16(Ay1.v, Bf.v, zero4);
    doY(Cy1, kT - 1);
  }
}

extern "C" void kernel_launch(void* const* d_in, const int* in_sizes, int n_in,
                              void* d_out, int out_size, void* d_ws,
                              size_t ws_size, hipStream_t stream) {
  const float* x = (const float*)d_in[0];
  const float* Wih = (const float*)d_in[1];
  const float* Whh = (const float*)d_in[2];
  const float* bih = (const float*)d_in[3];
  const float* bhh = (const float*)d_in[4];
  const float* W1 = (const float*)d_in[5];
  const float* b1 = (const float*)d_in[6];
  const float* W2 = (const float*)d_in[7];
  const float* b2 = (const float*)d_in[8];
  const float* W3 = (const float*)d_in[9];
  const float* b3 = (const float*)d_in[10];
  float* out = (float*)d_out;

  if (ws_size >= kWsNeed) {
    unsigned* hws = (unsigned*)d_ws;
    gru_mfma<<<dim3(kN * 8), dim3(64), 0, stream>>>(x, Wih, Whh, bih, bhh,
                                                    hws);
    mlp_mfma<<<dim3(kN * 8, 4), dim3(64), 0, stream>>>(hws, W1, b1, W2, b2, W3,
                                                       b3, out);
  } else {
    actor_mfma<<<dim3(kN * 8), dim3(64), 0, stream>>>(x, Wih, Whh, bih, bhh,
                                                      W1, b1, W2, b2, W3, b3,
                                                      out);
  }
}